// Round 3
// baseline (5313.431 us; speedup 1.0000x reference)
//
#include <hip/hip_runtime.h>

// SolarRNN: B=256, T=4096, F=16, H=64. One persistent block per sequence.
// 512 threads = 8 waves (2/SIMD). Output-split: wave w owns outputs
// [8w,8w+8); lane = (jo = l>>3, kc = l&7); kc indexes an 8-row K-chunk.
// Gate partials butterfly-reduced over kc IN REGISTERS (shfl_xor 1/2/4).
// Cross-wave exchange: double-buffered 64-float h1/o1/h2 vectors in LDS,
// ONE barrier per step. L2 of step i-1 pipelined against L1 of step i.
//
// R3 change: PIN all weights/biases in VGPRs with an opaque-copy asm.
// R1/R2 evidence (VGPR_Count 124/80, VALUBusy 62/52%) showed LLVM sinks the
// invariant global weight loads into the T-loop (~100 KB/step/CU of L1
// traffic = the bottleneck). asm("" : "+v") makes the loaded value
// non-rematerializable, forcing residency.

#define T_ 4096
#define L2E 1.4426950408889634f
#define KEEP(v_) asm volatile("" : "+v"(v_))

__device__ __forceinline__ float sigm(float x) {
    float e = __builtin_amdgcn_exp2f(-L2E * x);
    return __builtin_amdgcn_rcpf(1.0f + e);
}
__device__ __forceinline__ float tanh_(float x) {
    float e = __builtin_amdgcn_exp2f(2.0f * L2E * x);
    return 1.0f - 2.0f * __builtin_amdgcn_rcpf(1.0f + e);
}
// sum over lane bits 0..2 (the kc dimension); result in ALL lanes
__device__ __forceinline__ float bflyk(float v) {
    v += __shfl_xor(v, 1); v += __shfl_xor(v, 2); v += __shfl_xor(v, 4);
    return v;
}

__launch_bounds__(512, 2)
__global__ void solar_rnn(const float* __restrict__ x,
                          const float* __restrict__ Wi1, const float* __restrict__ bi1,
                          const float* __restrict__ Whr1, const float* __restrict__ Whz1,
                          const float* __restrict__ Whn1, const float* __restrict__ bhn1,
                          const float* __restrict__ Wi2, const float* __restrict__ bi2,
                          const float* __restrict__ Whr2, const float* __restrict__ Whz2,
                          const float* __restrict__ Whn2, const float* __restrict__ bhn2,
                          const float* __restrict__ Wp, const float* __restrict__ bp,
                          const float* __restrict__ Wa,
                          const float* __restrict__ W1, const float* __restrict__ b1,
                          const float* __restrict__ W2, const float* __restrict__ b2,
                          const float* __restrict__ W3, const float* __restrict__ b3,
                          const float* __restrict__ W4, const float* __restrict__ b4,
                          float* __restrict__ out)
{
    const int b   = blockIdx.x;
    const int tid = threadIdx.x;
    const int w   = tid >> 6;      // wave 0..7
    const int l   = tid & 63;
    const int kc  = l & 7;         // K-chunk (8 rows)
    const int j   = 8 * w + (l >> 3);    // global output index 0..63

    __shared__ __align__(16) float xbuf[2][1024];   // 64 steps x 16 feats, dbl-buf
    __shared__ __align__(16) float h1buf[2][64];
    __shared__ __align__(16) float o1buf[2][64];
    __shared__ __align__(16) float h2buf[2][64];
    __shared__ __align__(16) float spart[2][8];
    __shared__ float sm_a[128], sm_b[128];

    // ---- register-resident weight slices (PINNED) ----
    float whr1[8], whz1[8], whn1[8];   // layer-1 hidden kernels, rows 8kc.., col j
    float wr2[8],  wz2[8],  wn2[8];    // layer-2 hidden kernels
    float w2r[8],  w2z[8],  w2n[8];    // Wi2 (o1 -> gates)
    #pragma unroll
    for (int ii = 0; ii < 8; ++ii) {
        const int r8 = 8 * kc + ii;
        whr1[ii] = Whr1[r8 * 64 + j];
        whz1[ii] = Whz1[r8 * 64 + j];
        whn1[ii] = Whn1[r8 * 64 + j];
        wr2[ii]  = Whr2[r8 * 64 + j];
        wz2[ii]  = Whz2[r8 * 64 + j];
        wn2[ii]  = Whn2[r8 * 64 + j];
        w2r[ii]  = Wi2[r8 * 192 + j];
        w2z[ii]  = Wi2[r8 * 192 + 64 + j];
        w2n[ii]  = Wi2[r8 * 192 + 128 + j];
    }
    float wir[2], wiz[2], win[2], wxp[2];  // Wi1 / Wp (K=16 -> 2 rows per kc)
    #pragma unroll
    for (int ii = 0; ii < 2; ++ii) {
        const int r2 = 2 * kc + ii;
        wir[ii] = Wi1[r2 * 192 + j];
        wiz[ii] = Wi1[r2 * 192 + 64 + j];
        win[ii] = Wi1[r2 * 192 + 128 + j];
        wxp[ii] = Wp[r2 * 64 + j];
    }
    float bi1r = bi1[j], bi1z = bi1[64 + j], bi1n = bi1[128 + j], bh1 = bhn1[j];
    float bi2r = bi2[j], bi2z = bi2[64 + j], bi2n = bi2[128 + j], bh2 = bhn2[j];
    float bpj  = bp[j],  waj  = Wa[j];
    // ba: constant shift on pre-softmax scores -> softmax-invariant, skipped.

    // pin everything: compiler must NOT re-load these inside the T-loop
    #pragma unroll
    for (int ii = 0; ii < 8; ++ii) {
        KEEP(whr1[ii]); KEEP(whz1[ii]); KEEP(whn1[ii]);
        KEEP(wr2[ii]);  KEEP(wz2[ii]);  KEEP(wn2[ii]);
        KEEP(w2r[ii]);  KEEP(w2z[ii]);  KEEP(w2n[ii]);
    }
    #pragma unroll
    for (int ii = 0; ii < 2; ++ii) {
        KEEP(wir[ii]); KEEP(wiz[ii]); KEEP(win[ii]); KEEP(wxp[ii]);
    }
    KEEP(bi1r); KEEP(bi1z); KEEP(bi1n); KEEP(bh1);
    KEEP(bi2r); KEEP(bi2z); KEEP(bi2n); KEEP(bh2);
    KEEP(bpj);  KEEP(waj);

    float am = -3.0e38f, al = 0.f, aa = 0.f, o2_prev = 0.f;

    const float* xb = x + (size_t)b * (T_ * 16);

    // preamble: zero state (parity 1 is read by iter 0), stage x chunk 0
    if (tid < 64) { h1buf[1][tid] = 0.f; o1buf[1][tid] = 0.f; h2buf[1][tid] = 0.f; }
    {
        const float2 v = *(const float2*)(xb + 2 * tid);
        *(float2*)&xbuf[0][2 * tid] = v;
    }
    float2 xs = make_float2(0.f, 0.f);

    #pragma unroll 1
    for (int i = 0; i <= T_; ++i) {
        __syncthreads();
        const int p = i & 1, rp = p ^ 1;
        const int c = i >> 6;

        // x prefetch: load chunk c+1 at chunk start, commit to LDS mid-chunk
        if ((i & 63) == 0 && c < 63)
            xs = *(const float2*)(xb + (c + 1) * 1024 + 2 * tid);
        if ((i & 63) == 32 && c < 63)
            *(float2*)&xbuf[(c + 1) & 1][2 * tid] = xs;

        // ---- LDS reads (issue early; 1 barrier/step, dbl-buffered) ----
        float h1c[8], o1c[8], h2c[8];
        *(float4*)&h1c[0] = *(const float4*)&h1buf[rp][8 * kc];
        *(float4*)&h1c[4] = *(const float4*)&h1buf[rp][8 * kc + 4];
        *(float4*)&o1c[0] = *(const float4*)&o1buf[rp][8 * kc];
        *(float4*)&o1c[4] = *(const float4*)&o1buf[rp][8 * kc + 4];
        *(float4*)&h2c[0] = *(const float4*)&h2buf[rp][8 * kc];
        *(float4*)&h2c[4] = *(const float4*)&h2buf[rp][8 * kc + 4];
        const float h1pj = h1buf[rp][j];
        const float h2pj = h2buf[rp][j];
        const float o1pj = o1buf[rp][j];
        const float2 xv = *(const float2*)&xbuf[c & 1][(i & 63) * 16 + 2 * kc];

        // ---- softmax update for step i-2 (independent post-barrier filler) ----
        if (i >= 2) {
            const float4 s0 = *(const float4*)&spart[rp][0];
            const float4 s1 = *(const float4*)&spart[rp][4];
            const float s = ((s0.x + s0.y) + (s0.z + s0.w)) +
                            ((s1.x + s1.y) + (s1.z + s1.w));
            const float mn = fmaxf(am, s);
            const float ca = __builtin_amdgcn_exp2f((am - mn) * L2E);
            const float ce = __builtin_amdgcn_exp2f((s - mn) * L2E);
            al = fmaf(al, ca, ce);
            aa = fmaf(aa, ca, ce * o2_prev);
            am = mn;
        }

        // ---- L1 gate partials for step i ----
        float ar  = fmaf(xv.x, wir[0], xv.y * wir[1]);
        float az  = fmaf(xv.x, wiz[0], xv.y * wiz[1]);
        float ain = fmaf(xv.x, win[0], xv.y * win[1]);
        float axp = fmaf(xv.x, wxp[0], xv.y * wxp[1]);
        float ahn = 0.f;
        #pragma unroll
        for (int ii = 0; ii < 8; ++ii) {
            ar  = fmaf(h1c[ii], whr1[ii], ar);
            az  = fmaf(h1c[ii], whz1[ii], az);
            ahn = fmaf(h1c[ii], whn1[ii], ahn);
        }
        // ---- L2 gate partials for step i-1 (pipelined) ----
        float br = 0.f, bz = 0.f, bin = 0.f, bhn_ = 0.f;
        #pragma unroll
        for (int ii = 0; ii < 8; ++ii) {
            br   = fmaf(h2c[ii], wr2[ii], br);
            bz   = fmaf(h2c[ii], wz2[ii], bz);
            bhn_ = fmaf(h2c[ii], wn2[ii], bhn_);
            br   = fmaf(o1c[ii], w2r[ii], br);
            bz   = fmaf(o1c[ii], w2z[ii], bz);
            bin  = fmaf(o1c[ii], w2n[ii], bin);
        }

        // ---- butterfly reduce over kc + pointwise (all lanes, per-jo) ----
        ar = bflyk(ar); az = bflyk(az); ain = bflyk(ain);
        ahn = bflyk(ahn); axp = bflyk(axp);
        const float r1  = sigm(ar + bi1r);
        const float z1  = sigm(az + bi1z);
        const float n1  = tanh_((ain + bi1n) + r1 * (ahn + bh1));
        const float h1v = n1 + z1 * (h1pj - n1);
        const float o1v = h1v + 0.5f * (axp + bpj);

        br = bflyk(br); bz = bflyk(bz); bin = bflyk(bin); bhn_ = bflyk(bhn_);
        const float r2 = sigm(br + bi2r);
        const float z2 = sigm(bz + bi2z);
        const float n2 = tanh_((bin + bi2n) + r2 * (bhn_ + bh2));
        float h2v = n2 + z2 * (h2pj - n2);
        float o2v = h2v + 0.5f * o1pj;
        if (i == 0) { h2v = 0.f; o2v = 0.f; }   // step -1 is all-zero state

        // ---- score partial for step i-1: reduce over jo (lane bits 3..5) ----
        float sv = o2v * waj;
        sv += __shfl_xor(sv, 8); sv += __shfl_xor(sv, 16); sv += __shfl_xor(sv, 32);

        // ---- publish state ----
        if (kc == 0) {
            h1buf[p][j] = h1v;
            o1buf[p][j] = o1v;
            h2buf[p][j] = h2v;
        }
        if (l == 0) spart[p][w] = sv;
        o2_prev = o2v;
    }

    // drain: softmax update for step T-1 (spart parity of i=T_ is 0)
    __syncthreads();
    {
        const float4 s0 = *(const float4*)&spart[0][0];
        const float4 s1 = *(const float4*)&spart[0][4];
        const float s = ((s0.x + s0.y) + (s0.z + s0.w)) +
                        ((s1.x + s1.y) + (s1.z + s1.w));
        const float mn = fmaxf(am, s);
        const float ca = __builtin_amdgcn_exp2f((am - mn) * L2E);
        const float ce = __builtin_amdgcn_exp2f((s - mn) * L2E);
        al = fmaf(al, ca, ce);
        aa = fmaf(aa, ca, ce * o2_prev);
        am = mn;
    }

    // ---- attended vector + MLP tail ----
    const float att = aa / al;
    if (kc == 0) sm_a[j] = att;     // one writer per output j
    __syncthreads();

    float v1 = 0.f;
    if (tid < 128) {
        float a = b1[tid];
        for (int k = 0; k < 64; ++k) a = fmaf(sm_a[k], W1[k * 128 + tid], a);
        v1 = fmaxf(a, 0.f);
    }
    __syncthreads();
    if (tid < 128) sm_b[tid] = v1;
    __syncthreads();
    if (tid < 64) {
        float a = b2[tid];
        for (int k = 0; k < 128; ++k) a = fmaf(sm_b[k], W2[k * 64 + tid], a);
        sm_a[tid] = fmaxf(a, 0.f);
    }
    __syncthreads();
    if (tid < 32) {
        float a = b3[tid];
        for (int k = 0; k < 64; ++k) a = fmaf(sm_a[k], W3[k * 32 + tid], a);
        sm_b[tid] = fmaxf(a, 0.f);
    }
    __syncthreads();
    if (tid < 2) {
        float a = b4[tid];
        for (int k = 0; k < 32; ++k) a = fmaf(sm_b[k], W4[k * 2 + tid], a);
        out[b * 2 + tid] = a;
    }
}

extern "C" void kernel_launch(void* const* d_in, const int* in_sizes, int n_in,
                              void* d_out, int out_size, void* d_ws, size_t ws_size,
                              hipStream_t stream) {
    const float* x    = (const float*)d_in[0];
    const float* Wi1  = (const float*)d_in[1];
    const float* bi1  = (const float*)d_in[2];
    const float* Whr1 = (const float*)d_in[3];
    const float* Whz1 = (const float*)d_in[4];
    const float* Whn1 = (const float*)d_in[5];
    const float* bhn1 = (const float*)d_in[6];
    const float* Wi2  = (const float*)d_in[7];
    const float* bi2  = (const float*)d_in[8];
    const float* Whr2 = (const float*)d_in[9];
    const float* Whz2 = (const float*)d_in[10];
    const float* Whn2 = (const float*)d_in[11];
    const float* bhn2 = (const float*)d_in[12];
    const float* Wp   = (const float*)d_in[13];
    const float* bp   = (const float*)d_in[14];
    const float* Wa   = (const float*)d_in[15];
    // d_in[16] = ba: unused (softmax shift-invariant)
    const float* W1   = (const float*)d_in[17];
    const float* b1   = (const float*)d_in[18];
    const float* W2   = (const float*)d_in[19];
    const float* b2   = (const float*)d_in[20];
    const float* W3   = (const float*)d_in[21];
    const float* b3   = (const float*)d_in[22];
    const float* W4   = (const float*)d_in[23];
    const float* b4   = (const float*)d_in[24];

    solar_rnn<<<dim3(256), dim3(512), 0, stream>>>(
        x, Wi1, bi1, Whr1, Whz1, Whn1, bhn1,
        Wi2, bi2, Whr2, Whz2, Whn2, bhn2,
        Wp, bp, Wa, W1, b1, W2, b2, W3, b3, W4, b4,
        (float*)d_out);
}

// Round 4
// 5285.907 us; speedup vs baseline: 1.0052x; 1.0052x over previous
//
#include <hip/hip_runtime.h>

// SolarRNN: B=256, T=4096, F=16, H=64. One persistent block per sequence.
// 512 threads = 8 waves (2/SIMD). Output-split: wave w owns outputs
// [8w,8w+8); lane = (jo = l>>3, kc = l&7); kc indexes an 8-row K-chunk.
// Gate partials butterfly-reduced over kc IN REGISTERS (shfl_xor 1/2/4).
// Cross-wave exchange: double-buffered 64-float h1/o1/h2 vectors in LDS,
// ONE barrier per step. L2 of step i-1 pipelined against L1 of step i.
//
// R4 change: amdgpu_waves_per_eu(2,2). R2/R3 evidence (VGPR_Count=80 with
// AND without pins, dur identical, both matching an L1-refill-bound model of
// ~180 KB/step/CU) shows the scheduler targets max-occupancy (range [2,8]
// from launch_bounds) and spills the weights to reach ~6 waves/EU. Grid is
// 1 block/CU, so occupancy >2 waves/EU is worthless: pin the range to
// exactly 2 -> pressure budget 256 VGPR/wave -> weights stay resident.

#define T_ 4096
#define L2E 1.4426950408889634f
#define KEEP(v_) asm volatile("" : "+v"(v_))

__device__ __forceinline__ float sigm(float x) {
    float e = __builtin_amdgcn_exp2f(-L2E * x);
    return __builtin_amdgcn_rcpf(1.0f + e);
}
__device__ __forceinline__ float tanh_(float x) {
    float e = __builtin_amdgcn_exp2f(2.0f * L2E * x);
    return 1.0f - 2.0f * __builtin_amdgcn_rcpf(1.0f + e);
}
// sum over lane bits 0..2 (the kc dimension); result in ALL lanes
__device__ __forceinline__ float bflyk(float v) {
    v += __shfl_xor(v, 1); v += __shfl_xor(v, 2); v += __shfl_xor(v, 4);
    return v;
}

__global__ void
__attribute__((amdgpu_flat_work_group_size(512, 512), amdgpu_waves_per_eu(2, 2)))
solar_rnn(const float* __restrict__ x,
          const float* __restrict__ Wi1, const float* __restrict__ bi1,
          const float* __restrict__ Whr1, const float* __restrict__ Whz1,
          const float* __restrict__ Whn1, const float* __restrict__ bhn1,
          const float* __restrict__ Wi2, const float* __restrict__ bi2,
          const float* __restrict__ Whr2, const float* __restrict__ Whz2,
          const float* __restrict__ Whn2, const float* __restrict__ bhn2,
          const float* __restrict__ Wp, const float* __restrict__ bp,
          const float* __restrict__ Wa,
          const float* __restrict__ W1, const float* __restrict__ b1,
          const float* __restrict__ W2, const float* __restrict__ b2,
          const float* __restrict__ W3, const float* __restrict__ b3,
          const float* __restrict__ W4, const float* __restrict__ b4,
          float* __restrict__ out)
{
    const int b   = blockIdx.x;
    const int tid = threadIdx.x;
    const int w   = tid >> 6;      // wave 0..7
    const int l   = tid & 63;
    const int kc  = l & 7;         // K-chunk (8 rows)
    const int j   = 8 * w + (l >> 3);    // global output index 0..63

    __shared__ __align__(16) float xbuf[2][1024];   // 64 steps x 16 feats, dbl-buf
    __shared__ __align__(16) float h1buf[2][64];
    __shared__ __align__(16) float o1buf[2][64];
    __shared__ __align__(16) float h2buf[2][64];
    __shared__ __align__(16) float spart[2][8];
    __shared__ float sm_a[128], sm_b[128];

    // ---- register-resident weight slices (PINNED) ----
    float whr1[8], whz1[8], whn1[8];   // layer-1 hidden kernels, rows 8kc.., col j
    float wr2[8],  wz2[8],  wn2[8];    // layer-2 hidden kernels
    float w2r[8],  w2z[8],  w2n[8];    // Wi2 (o1 -> gates)
    #pragma unroll
    for (int ii = 0; ii < 8; ++ii) {
        const int r8 = 8 * kc + ii;
        whr1[ii] = Whr1[r8 * 64 + j];
        whz1[ii] = Whz1[r8 * 64 + j];
        whn1[ii] = Whn1[r8 * 64 + j];
        wr2[ii]  = Whr2[r8 * 64 + j];
        wz2[ii]  = Whz2[r8 * 64 + j];
        wn2[ii]  = Whn2[r8 * 64 + j];
        w2r[ii]  = Wi2[r8 * 192 + j];
        w2z[ii]  = Wi2[r8 * 192 + 64 + j];
        w2n[ii]  = Wi2[r8 * 192 + 128 + j];
    }
    float wir[2], wiz[2], win[2], wxp[2];  // Wi1 / Wp (K=16 -> 2 rows per kc)
    #pragma unroll
    for (int ii = 0; ii < 2; ++ii) {
        const int r2 = 2 * kc + ii;
        wir[ii] = Wi1[r2 * 192 + j];
        wiz[ii] = Wi1[r2 * 192 + 64 + j];
        win[ii] = Wi1[r2 * 192 + 128 + j];
        wxp[ii] = Wp[r2 * 64 + j];
    }
    float bi1r = bi1[j], bi1z = bi1[64 + j], bi1n = bi1[128 + j], bh1 = bhn1[j];
    float bi2r = bi2[j], bi2z = bi2[64 + j], bi2n = bi2[128 + j], bh2 = bhn2[j];
    float bpj  = bp[j],  waj  = Wa[j];
    // ba: constant shift on pre-softmax scores -> softmax-invariant, skipped.

    // pin everything: compiler must NOT re-load these inside the T-loop
    #pragma unroll
    for (int ii = 0; ii < 8; ++ii) {
        KEEP(whr1[ii]); KEEP(whz1[ii]); KEEP(whn1[ii]);
        KEEP(wr2[ii]);  KEEP(wz2[ii]);  KEEP(wn2[ii]);
        KEEP(w2r[ii]);  KEEP(w2z[ii]);  KEEP(w2n[ii]);
    }
    #pragma unroll
    for (int ii = 0; ii < 2; ++ii) {
        KEEP(wir[ii]); KEEP(wiz[ii]); KEEP(win[ii]); KEEP(wxp[ii]);
    }
    KEEP(bi1r); KEEP(bi1z); KEEP(bi1n); KEEP(bh1);
    KEEP(bi2r); KEEP(bi2z); KEEP(bi2n); KEEP(bh2);
    KEEP(bpj);  KEEP(waj);

    float am = -3.0e38f, al = 0.f, aa = 0.f, o2_prev = 0.f;

    const float* xb = x + (size_t)b * (T_ * 16);

    // preamble: zero state (parity 1 is read by iter 0), stage x chunk 0
    if (tid < 64) { h1buf[1][tid] = 0.f; o1buf[1][tid] = 0.f; h2buf[1][tid] = 0.f; }
    {
        const float2 v = *(const float2*)(xb + 2 * tid);
        *(float2*)&xbuf[0][2 * tid] = v;
    }
    float2 xs = make_float2(0.f, 0.f);

    #pragma unroll 1
    for (int i = 0; i <= T_; ++i) {
        __syncthreads();
        const int p = i & 1, rp = p ^ 1;
        const int c = i >> 6;

        // x prefetch: load chunk c+1 at chunk start, commit to LDS mid-chunk
        if ((i & 63) == 0 && c < 63)
            xs = *(const float2*)(xb + (c + 1) * 1024 + 2 * tid);
        if ((i & 63) == 32 && c < 63)
            *(float2*)&xbuf[(c + 1) & 1][2 * tid] = xs;

        // ---- LDS reads (issue early; 1 barrier/step, dbl-buffered) ----
        float h1c[8], o1c[8], h2c[8];
        *(float4*)&h1c[0] = *(const float4*)&h1buf[rp][8 * kc];
        *(float4*)&h1c[4] = *(const float4*)&h1buf[rp][8 * kc + 4];
        *(float4*)&o1c[0] = *(const float4*)&o1buf[rp][8 * kc];
        *(float4*)&o1c[4] = *(const float4*)&o1buf[rp][8 * kc + 4];
        *(float4*)&h2c[0] = *(const float4*)&h2buf[rp][8 * kc];
        *(float4*)&h2c[4] = *(const float4*)&h2buf[rp][8 * kc + 4];
        const float h1pj = h1buf[rp][j];
        const float h2pj = h2buf[rp][j];
        const float o1pj = o1buf[rp][j];
        const float2 xv = *(const float2*)&xbuf[c & 1][(i & 63) * 16 + 2 * kc];

        // ---- softmax update for step i-2 (independent post-barrier filler) ----
        if (i >= 2) {
            const float4 s0 = *(const float4*)&spart[rp][0];
            const float4 s1 = *(const float4*)&spart[rp][4];
            const float s = ((s0.x + s0.y) + (s0.z + s0.w)) +
                            ((s1.x + s1.y) + (s1.z + s1.w));
            const float mn = fmaxf(am, s);
            const float ca = __builtin_amdgcn_exp2f((am - mn) * L2E);
            const float ce = __builtin_amdgcn_exp2f((s - mn) * L2E);
            al = fmaf(al, ca, ce);
            aa = fmaf(aa, ca, ce * o2_prev);
            am = mn;
        }

        // ---- L1 gate partials for step i ----
        float ar  = fmaf(xv.x, wir[0], xv.y * wir[1]);
        float az  = fmaf(xv.x, wiz[0], xv.y * wiz[1]);
        float ain = fmaf(xv.x, win[0], xv.y * win[1]);
        float axp = fmaf(xv.x, wxp[0], xv.y * wxp[1]);
        float ahn = 0.f;
        #pragma unroll
        for (int ii = 0; ii < 8; ++ii) {
            ar  = fmaf(h1c[ii], whr1[ii], ar);
            az  = fmaf(h1c[ii], whz1[ii], az);
            ahn = fmaf(h1c[ii], whn1[ii], ahn);
        }
        // ---- L2 gate partials for step i-1 (pipelined) ----
        float br = 0.f, bz = 0.f, bin = 0.f, bhn_ = 0.f;
        #pragma unroll
        for (int ii = 0; ii < 8; ++ii) {
            br   = fmaf(h2c[ii], wr2[ii], br);
            bz   = fmaf(h2c[ii], wz2[ii], bz);
            bhn_ = fmaf(h2c[ii], wn2[ii], bhn_);
            br   = fmaf(o1c[ii], w2r[ii], br);
            bz   = fmaf(o1c[ii], w2z[ii], bz);
            bin  = fmaf(o1c[ii], w2n[ii], bin);
        }

        // ---- butterfly reduce over kc + pointwise (all lanes, per-jo) ----
        ar = bflyk(ar); az = bflyk(az); ain = bflyk(ain);
        ahn = bflyk(ahn); axp = bflyk(axp);
        const float r1  = sigm(ar + bi1r);
        const float z1  = sigm(az + bi1z);
        const float n1  = tanh_((ain + bi1n) + r1 * (ahn + bh1));
        const float h1v = n1 + z1 * (h1pj - n1);
        const float o1v = h1v + 0.5f * (axp + bpj);

        br = bflyk(br); bz = bflyk(bz); bin = bflyk(bin); bhn_ = bflyk(bhn_);
        const float r2 = sigm(br + bi2r);
        const float z2 = sigm(bz + bi2z);
        const float n2 = tanh_((bin + bi2n) + r2 * (bhn_ + bh2));
        float h2v = n2 + z2 * (h2pj - n2);
        float o2v = h2v + 0.5f * o1pj;
        if (i == 0) { h2v = 0.f; o2v = 0.f; }   // step -1 is all-zero state

        // ---- score partial for step i-1: reduce over jo (lane bits 3..5) ----
        float sv = o2v * waj;
        sv += __shfl_xor(sv, 8); sv += __shfl_xor(sv, 16); sv += __shfl_xor(sv, 32);

        // ---- publish state ----
        if (kc == 0) {
            h1buf[p][j] = h1v;
            o1buf[p][j] = o1v;
            h2buf[p][j] = h2v;
        }
        if (l == 0) spart[p][w] = sv;
        o2_prev = o2v;
    }

    // drain: softmax update for step T-1 (spart parity of i=T_ is 0)
    __syncthreads();
    {
        const float4 s0 = *(const float4*)&spart[0][0];
        const float4 s1 = *(const float4*)&spart[0][4];
        const float s = ((s0.x + s0.y) + (s0.z + s0.w)) +
                        ((s1.x + s1.y) + (s1.z + s1.w));
        const float mn = fmaxf(am, s);
        const float ca = __builtin_amdgcn_exp2f((am - mn) * L2E);
        const float ce = __builtin_amdgcn_exp2f((s - mn) * L2E);
        al = fmaf(al, ca, ce);
        aa = fmaf(aa, ca, ce * o2_prev);
        am = mn;
    }

    // ---- attended vector + MLP tail ----
    const float att = aa / al;
    if (kc == 0) sm_a[j] = att;     // one writer per output j
    __syncthreads();

    float v1 = 0.f;
    if (tid < 128) {
        float a = b1[tid];
        for (int k = 0; k < 64; ++k) a = fmaf(sm_a[k], W1[k * 128 + tid], a);
        v1 = fmaxf(a, 0.f);
    }
    __syncthreads();
    if (tid < 128) sm_b[tid] = v1;
    __syncthreads();
    if (tid < 64) {
        float a = b2[tid];
        for (int k = 0; k < 128; ++k) a = fmaf(sm_b[k], W2[k * 64 + tid], a);
        sm_a[tid] = fmaxf(a, 0.f);
    }
    __syncthreads();
    if (tid < 32) {
        float a = b3[tid];
        for (int k = 0; k < 64; ++k) a = fmaf(sm_a[k], W3[k * 32 + tid], a);
        sm_b[tid] = fmaxf(a, 0.f);
    }
    __syncthreads();
    if (tid < 2) {
        float a = b4[tid];
        for (int k = 0; k < 32; ++k) a = fmaf(sm_b[k], W4[k * 2 + tid], a);
        out[b * 2 + tid] = a;
    }
}

extern "C" void kernel_launch(void* const* d_in, const int* in_sizes, int n_in,
                              void* d_out, int out_size, void* d_ws, size_t ws_size,
                              hipStream_t stream) {
    const float* x    = (const float*)d_in[0];
    const float* Wi1  = (const float*)d_in[1];
    const float* bi1  = (const float*)d_in[2];
    const float* Whr1 = (const float*)d_in[3];
    const float* Whz1 = (const float*)d_in[4];
    const float* Whn1 = (const float*)d_in[5];
    const float* bhn1 = (const float*)d_in[6];
    const float* Wi2  = (const float*)d_in[7];
    const float* bi2  = (const float*)d_in[8];
    const float* Whr2 = (const float*)d_in[9];
    const float* Whz2 = (const float*)d_in[10];
    const float* Whn2 = (const float*)d_in[11];
    const float* bhn2 = (const float*)d_in[12];
    const float* Wp   = (const float*)d_in[13];
    const float* bp   = (const float*)d_in[14];
    const float* Wa   = (const float*)d_in[15];
    // d_in[16] = ba: unused (softmax shift-invariant)
    const float* W1   = (const float*)d_in[17];
    const float* b1   = (const float*)d_in[18];
    const float* W2   = (const float*)d_in[19];
    const float* b2   = (const float*)d_in[20];
    const float* W3   = (const float*)d_in[21];
    const float* b3   = (const float*)d_in[22];
    const float* W4   = (const float*)d_in[23];
    const float* b4   = (const float*)d_in[24];

    solar_rnn<<<dim3(256), dim3(512), 0, stream>>>(
        x, Wi1, bi1, Whr1, Whz1, Whn1, bhn1,
        Wi2, bi2, Whr2, Whz2, Whn2, bhn2,
        Wp, bp, Wa, W1, b1, W2, b2, W3, b3, W4, b4,
        (float*)d_out);
}